// Round 17
// baseline (785.564 us; speedup 1.0000x reference)
//
#include <hip/hip_runtime.h>
#include <hip/hip_fp16.h>
#include <stdint.h>

#define E_N 200000
#define A_N 1000000

typedef short s16x8 __attribute__((ext_vector_type(8)));
typedef short s16x4 __attribute__((ext_vector_type(4)));
typedef float f32x4 __attribute__((ext_vector_type(4)));
typedef uint32_t u32x4 __attribute__((ext_vector_type(4)));
typedef uint32_t u32x2 __attribute__((ext_vector_type(2)));
typedef int i32x4 __attribute__((ext_vector_type(4)));
typedef _Float16 f16x8 __attribute__((ext_vector_type(8)));

__device__ __forceinline__ ushort f2bf(float f) {
  uint32_t x = __float_as_uint(f);
  uint32_t r = x + 0x7FFFu + ((x >> 16) & 1u);
  return (ushort)(r >> 16);
}

__device__ __forceinline__ ushort f2h(float f) {
  return __half_as_ushort(__float2half(f));
}

__device__ __forceinline__ uint32_t cvtpk(float lo, float hi) {
  uint32_t r;
  asm("v_cvt_pk_bf16_f32 %0, %1, %2" : "=v"(r) : "v"(lo), "v"(hi));
  return r;
}

__device__ __forceinline__ uint32_t pkmul(uint32_t a, uint32_t b) {
  uint32_t r;
  asm("v_pk_mul_f16 %0, %1, %2" : "=v"(r) : "v"(a), "v"(b));
  return r;
}

__device__ __forceinline__ float silu_f(float v) {
  return v * (1.0f / (1.0f + __expf(-v)));
}

// swizzled element offset within a [rows][128] 16-bit tile (XOR bank-swizzle)
__device__ __forceinline__ int swz(int row, int h) {
  return row * 128 + (h ^ ((row & 7) << 3));
}

// element offset in a 2KB per-wave scratch: 16 rows x 64 cols (col mod 64)
__device__ __forceinline__ int sws(int r, int c) {
  return r * 64 + ((c & 63) ^ ((r & 7) << 3));
}

// C-layout f32 -> B-frags via 2 half-passes through 2KB wave scratch.
__device__ __forceinline__ void exchCtoB(ushort* scw, int r15, int hi,
                                         const f32x4* xv, s16x8* st) {
  u32x2 pk[8];
#pragma unroll
  for (int nt = 0; nt < 8; nt++) {
    pk[nt][0] = cvtpk(xv[nt][0], xv[nt][1]);
    pk[nt][1] = cvtpk(xv[nt][2], xv[nt][3]);
  }
#pragma unroll
  for (int nt = 0; nt < 4; nt++)
    *(u32x2*)&scw[sws(r15, nt * 16 + hi * 4)] = pk[nt];
#pragma unroll
  for (int k = 0; k < 2; k++)
    st[k] = *(const s16x8*)&scw[sws(r15, k * 32 + hi * 8)];
#pragma unroll
  for (int nt = 4; nt < 8; nt++)
    *(u32x2*)&scw[sws(r15, nt * 16 + hi * 4)] = pk[nt];
#pragma unroll
  for (int k = 2; k < 4; k++)
    st[k] = *(const s16x8*)&scw[sws(r15, k * 32 + hi * 8)];
}

// B-frags -> C-layout bf16 pairs
__device__ __forceinline__ void exchBtoC(ushort* scw, int r15, int hi,
                                         const s16x8* stv, u32x2* mc) {
#pragma unroll
  for (int k = 0; k < 2; k++)
    *(s16x8*)&scw[sws(r15, k * 32 + hi * 8)] = stv[k];
#pragma unroll
  for (int nt = 0; nt < 4; nt++)
    mc[nt] = *(const u32x2*)&scw[sws(r15, nt * 16 + hi * 4)];
#pragma unroll
  for (int k = 2; k < 4; k++)
    *(s16x8*)&scw[sws(r15, k * 32 + hi * 8)] = stv[k];
#pragma unroll
  for (int nt = 4; nt < 8; nt++)
    mc[nt] = *(const u32x2*)&scw[sws(r15, nt * 16 + hi * 4)];
}

// ---------------- prep: wg_bil -> f16; wg_lin -> bf16; transposed, swizzled --
__global__ __launch_bounds__(256) void k_prep(
    const float* __restrict__ Wbil, const float* __restrict__ Wsrc,
    const float* __restrict__ Wtgt, const float* __restrict__ WresB,
    const float* __restrict__ Wskip, const float* __restrict__ WresA,
    const float* __restrict__ bsrc, const float* __restrict__ btgt,
    const float* __restrict__ bresB, const float* __restrict__ bskip,
    const float* __restrict__ bresA,
    ushort* __restrict__ wg_bil, ushort* __restrict__ wg_lin,
    float* __restrict__ bias_tab) {
  int tid = blockIdx.x * 256 + threadIdx.x;
  if (tid < 8 * 16384) {
    int b = tid >> 14, r = tid & 16383;
    int i = r >> 7, h = r & 127;
    wg_bil[b * 16384 + swz(i, h)] = f2h(Wbil[(i * 8 + b) * 128 + h]);
    return;
  }
  tid -= 8 * 16384;
  if (tid < 9 * 16384) {
    int s = tid >> 14, r = tid & 16383;
    int c = r >> 7, h = r & 127;
    const float* src;
    switch (s) {
      case 0: src = Wsrc; break;
      case 1: src = Wtgt; break;
      case 2: src = WresB; break;
      case 3: src = WresB + 16384; break;
      case 4: src = Wskip; break;
      case 5: src = WresA; break;
      case 6: src = WresA + 16384; break;
      case 7: src = WresA + 32768; break;
      default: src = WresA + 49152; break;
    }
    wg_lin[s * 16384 + swz(c, h)] = f2bf(src[h * 128 + c]);
    return;
  }
  tid -= 9 * 16384;
  if (tid < 9 * 128) {
    int s = tid >> 7, c = tid & 127;
    const float* src;
    switch (s) {
      case 0: src = bsrc; break;
      case 1: src = btgt; break;
      case 2: src = bresB; break;
      case 3: src = bresB + 128; break;
      case 4: src = bskip; break;
      case 5: src = bresA; break;
      case 6: src = bresA + 128; break;
      case 7: src = bresA + 256; break;
      default: src = bresA + 384; break;
    }
    bias_tab[s * 128 + c] = src[c];
  }
}

// ---------------- sort-by-target infrastructure ------------------------------
__global__ __launch_bounds__(256) void k_hist(const int* __restrict__ aidx,
                                              int* __restrict__ cnt) {
  int i = blockIdx.x * 256 + threadIdx.x;
  if (i < A_N) atomicAdd(&cnt[aidx[A_N + i]], 1);
}

__global__ __launch_bounds__(256) void k_scan1(const int* __restrict__ cnt,
                                               int* __restrict__ excl,
                                               int* __restrict__ bsum) {
  __shared__ int s[256];
  int t = threadIdx.x;
  int base = blockIdx.x * 1024 + t * 4;
  int v[4];
#pragma unroll
  for (int j = 0; j < 4; j++) v[j] = (base + j < E_N) ? cnt[base + j] : 0;
  int sum = v[0] + v[1] + v[2] + v[3];
  s[t] = sum;
  __syncthreads();
#pragma unroll
  for (int d = 1; d < 256; d <<= 1) {
    int x = (t >= d) ? s[t - d] : 0;
    __syncthreads();
    s[t] += x;
    __syncthreads();
  }
  int run = s[t] - sum;
#pragma unroll
  for (int j = 0; j < 4; j++) {
    if (base + j < E_N) excl[base + j] = run;
    run += v[j];
  }
  if (t == 255) bsum[blockIdx.x] = s[255];
}

__global__ __launch_bounds__(256) void k_scan2(int* __restrict__ bsum, int nb) {
  __shared__ int s[256];
  int t = threadIdx.x;
  int orig = (t < nb) ? bsum[t] : 0;
  s[t] = orig;
  __syncthreads();
#pragma unroll
  for (int d = 1; d < 256; d <<= 1) {
    int x = (t >= d) ? s[t - d] : 0;
    __syncthreads();
    s[t] += x;
    __syncthreads();
  }
  if (t < nb) bsum[t] = s[t] - orig;
}

__global__ __launch_bounds__(256) void k_scan3(const int* __restrict__ excl,
                                               const int* __restrict__ bsum,
                                               int* __restrict__ cursor) {
  int t = threadIdx.x;
  int base = blockIdx.x * 1024 + t * 4;
  int add = bsum[blockIdx.x];
#pragma unroll
  for (int j = 0; j < 4; j++)
    if (base + j < E_N) cursor[base + j] = excl[base + j] + add;
}

// scatter + fused a-conversion: writes sorted te/se and pre-converted
// duplicated-f16 a pairs at the sorted position.
__global__ __launch_bounds__(256) void k_scatter(const int* __restrict__ aidx,
                                                 int* __restrict__ cursor,
                                                 const float* __restrict__ a_ws,
                                                 int* __restrict__ ste,
                                                 int* __restrict__ sse,
                                                 u32x4* __restrict__ a_srt) {
  int i = blockIdx.x * 256 + threadIdx.x;
  if (i < A_N) {
    int te = aidx[A_N + i];
    int se = aidx[i];
    int pos = atomicAdd(&cursor[te], 1);
    ste[pos] = te;
    sse[pos] = se;
    f32x4 a0 = *(const f32x4*)&a_ws[(size_t)i * 8];
    f32x4 a1 = *(const f32x4*)&a_ws[(size_t)i * 8 + 4];
    u32x4 o0, o1;
#pragma unroll
    for (int j = 0; j < 4; j++) {
      uint32_t h0 = f2h(a0[j]), h1 = f2h(a1[j]);
      o0[j] = (h0 << 16) | h0;
      o1[j] = (h1 << 16) | h1;
    }
    a_srt[(size_t)pos * 2] = o0;
    a_srt[(size_t)pos * 2 + 1] = o1;
  }
}

// ---------------- K1: a = angle.reshape(A,42) @ W_angle  -> [A,8] f32 --------
__global__ __launch_bounds__(256) void k_angle(const float* __restrict__ ang,
                                               const float* __restrict__ Wang,
                                               float* __restrict__ a_ws) {
  __shared__ float rows[128 * 42];
  __shared__ float wbuf[42 * 8];
  int t = threadIdx.x;
  int tile0 = blockIdx.x * 128;
  int nrows = A_N - tile0; if (nrows > 128) nrows = 128;
  if (nrows == 128) {
    const f32x4* src = (const f32x4*)(ang + (size_t)tile0 * 42);
    f32x4* dst = (f32x4*)rows;
    for (int k = t; k < 1344; k += 256) dst[k] = src[k];
  } else {
    int cnt = nrows * 42;
    for (int k = t; k < cnt; k += 256) rows[k] = ang[(size_t)tile0 * 42 + k];
  }
  for (int k = t; k < 336; k += 256) wbuf[k] = Wang[k];
  __syncthreads();
  int row = t >> 1, half = t & 1;
  if (row < nrows) {
    float a0 = 0.f, a1 = 0.f, a2 = 0.f, a3 = 0.f;
    const float* rp = &rows[row * 42];
    const float* wp = &wbuf[half * 4];
#pragma unroll
    for (int k = 0; k < 42; k++) {
      float v = rp[k];
      a0 += v * wp[k * 8 + 0]; a1 += v * wp[k * 8 + 1];
      a2 += v * wp[k * 8 + 2]; a3 += v * wp[k * 8 + 3];
    }
    f32x4 o; o.x = a0; o.y = a1; o.z = a2; o.w = a3;
    *(f32x4*)&a_ws[(tile0 + row) * 8 + half * 4] = o;
  }
}

// ---------------- Kd: d = dist @ W_dist  -> [E,128] f16 ----------------------
__global__ __launch_bounds__(256) void k_dist(const float* __restrict__ dist,
                                              const float* __restrict__ Wd,
                                              ushort* __restrict__ dtab) {
  __shared__ float w[6 * 128];
  int t = threadIdx.x;
  for (int k = t; k < 768; k += 256) w[k] = Wd[k];
  __syncthreads();
  int gid = blockIdx.x * 256 + t;
  int e = gid >> 2, q = gid & 3;
  if (e >= E_N) return;
  float dv[6];
#pragma unroll
  for (int r = 0; r < 6; r++) dv[r] = dist[e * 6 + r];
#pragma unroll
  for (int j = 0; j < 32; j += 4) {
    int c = q * 32 + j;
    s16x4 o;
#pragma unroll
    for (int jj = 0; jj < 4; jj++) {
      float s = 0.f;
#pragma unroll
      for (int r = 0; r < 6; r++) s += dv[r] * w[r * 128 + c + jj];
      o[jj] = (short)f2h(s);
    }
    *(s16x4*)&dtab[e * 128 + c] = o;
  }
}

// ---------------- K2: srcm = message @ W_src + b_src (bf16 MFMA) -> f16 ------
__global__ __launch_bounds__(512) void k_srcm(const float* __restrict__ msg,
                                              const ushort* __restrict__ wg_lin,
                                              const float* __restrict__ bias_tab,
                                              ushort* __restrict__ srcm) {
  __shared__ ushort xb[128 * 128];
  __shared__ ushort wb[16384];
  __shared__ float bias[128];
  int t = threadIdx.x;
  int tile0 = blockIdx.x * 128;
  const f32x4 Z4 = {0.f, 0.f, 0.f, 0.f};
  for (int off = t * 8; off < 16384; off += 4096)
    *(s16x8*)&wb[off] = *(const s16x8*)&wg_lin[off];
  if (t < 128) bias[t] = bias_tab[t];
  {
    int row = t >> 2, l = t & 3;
    int grow = tile0 + row;
#pragma unroll
    for (int j = 0; j < 8; j++) {
      int h = l * 32 + j * 4;
      s16x4 o; o[0] = 0; o[1] = 0; o[2] = 0; o[3] = 0;
      if (grow < E_N) {
        f32x4 v = *(const f32x4*)&msg[(size_t)grow * 128 + h];
        o[0] = (short)f2bf(v.x); o[1] = (short)f2bf(v.y);
        o[2] = (short)f2bf(v.z); o[3] = (short)f2bf(v.w);
      }
      *(s16x4*)&xb[swz(row, h)] = o;
    }
  }
  __syncthreads();
  int w = t >> 6, lane = t & 63;
  int rbase = w * 16;
  int arow = rbase + (lane & 15);
  int k0 = (lane >> 4) * 8;
  int r0 = (lane >> 4) * 4;
  f32x4 acc[8];
#pragma unroll
  for (int k = 0; k < 4; k++) {
    s16x8 af = *(const s16x8*)&xb[swz(arow, k * 32 + k0)];
#pragma unroll
    for (int nt = 0; nt < 8; nt++) {
      s16x8 bf = *(const s16x8*)&wb[swz(nt * 16 + (lane & 15), k * 32 + k0)];
      acc[nt] = __builtin_amdgcn_mfma_f32_16x16x32_bf16(af, bf, k == 0 ? Z4 : acc[nt], 0, 0, 0);
    }
  }
#pragma unroll
  for (int nt = 0; nt < 8; nt++) {
    int col = nt * 16 + (lane & 15);
    float bv = bias[col];
#pragma unroll
    for (int r = 0; r < 4; r++) {
      int grow = tile0 + rbase + r0 + r;
      if (grow < E_N) srcm[(size_t)grow * 128 + col] = f2h(acc[nt][r] + bv);
    }
  }
}

// ---------------- K3: sorted gather + bilinear f16 MFMA, 1-buffer, 3 blk/CU --
__global__ __launch_bounds__(256, 3) void k_bil(const int* __restrict__ sse,
                                                const ushort* __restrict__ srcm,
                                                const ushort* __restrict__ dtab,
                                                const u32x4* __restrict__ a_srt,
                                                const ushort* __restrict__ wg_bil,
                                                const int* __restrict__ ste,
                                                float* __restrict__ agg) {
  __shared__ ushort wb[16384];   // 32 KB single buffer (f16, pre-swizzled)
  int t = threadIdx.x;
  int lane = t & 63, w = t >> 6;
  int tile0 = blockIdx.x * 128;
  int mb = w * 32;
  int r15 = lane & 15, hi = lane >> 4;
  int k0 = hi * 8;
  int r0 = hi * 4;
  const f32x4 Z4 = {0.f, 0.f, 0.f, 0.f};

  // stage b=0
  {
    const ushort* gs = wg_bil + w * 4096 + lane * 8;
    ushort* ls = &wb[w * 4096];
#pragma unroll
    for (int i = 0; i < 8; i++)
      __builtin_amdgcn_global_load_lds(
          (const __attribute__((address_space(1))) void*)(gs + i * 512),
          (__attribute__((address_space(3))) void*)(ls + i * 512), 16, 0, 0);
  }

  // gather sm = srcm[src]*d[tgt] in PACKED f16; all index loads coalesced
  u32x4 smv[2][4];      // [mt][k]: 4 u32 = 8 f16
  uint32_t avd[2][8];   // a_b duplicated f16 pairs (pre-converted)
  int teo[2][4];
#pragma unroll
  for (int mt = 0; mt < 2; mt++) {
    int grow = tile0 + mb + mt * 16 + r15;
    int ok = (grow < A_N);
    int se = ok ? sse[grow] : 0;
    int te = ok ? ste[grow] : 0;
    if (ok) {
      u32x4 o0 = a_srt[(size_t)grow * 2];
      u32x4 o1 = a_srt[(size_t)grow * 2 + 1];
#pragma unroll
      for (int j = 0; j < 4; j++) { avd[mt][j] = o0[j]; avd[mt][4 + j] = o1[j]; }
    } else {
#pragma unroll
      for (int j = 0; j < 8; j++) avd[mt][j] = 0u;
    }
#pragma unroll
    for (int k = 0; k < 4; k++) {
      u32x4 sv = *(const u32x4*)&srcm[(size_t)se * 128 + k * 32 + k0];
      u32x4 dv = *(const u32x4*)&dtab[(size_t)te * 128 + k * 32 + k0];
#pragma unroll
      for (int j = 0; j < 4; j++) smv[mt][k][j] = pkmul(sv[j], dv[j]);
    }
    int orow0 = tile0 + mb + mt * 16 + r0;
    if (orow0 + 3 < A_N) {
      i32x4 tq = *(const i32x4*)&ste[orow0];
#pragma unroll
      for (int r = 0; r < 4; r++) teo[mt][r] = tq[r];
    } else {
#pragma unroll
      for (int r = 0; r < 4; r++)
        teo[mt][r] = (orow0 + r < A_N) ? ste[orow0 + r] : 0;
    }
  }

  f32x4 OUT[2][8];
#pragma unroll
  for (int mt = 0; mt < 2; mt++)
#pragma unroll
    for (int nt = 0; nt < 8; nt++) OUT[mt][nt] = Z4;

  __syncthreads();  // b=0 staged

#pragma unroll
  for (int b = 0; b < 8; b++) {
    uint32_t a0b = avd[0][b], a1b = avd[1][b];
    __builtin_amdgcn_s_setprio(1);
#pragma unroll
    for (int k = 0; k < 4; k++) {
      u32x4 p0, p1;
#pragma unroll
      for (int j = 0; j < 4; j++) {
        p0[j] = pkmul(smv[0][k][j], a0b);
        p1[j] = pkmul(smv[1][k][j], a1b);
      }
      f16x8 af0 = __builtin_bit_cast(f16x8, p0);
      f16x8 af1 = __builtin_bit_cast(f16x8, p1);
#pragma unroll
      for (int nt = 0; nt < 8; nt++) {
        f16x8 bf = *(const f16x8*)&wb[swz(nt * 16 + r15, k * 32 + k0)];
        OUT[0][nt] = __builtin_amdgcn_mfma_f32_16x16x32_f16(af0, bf, OUT[0][nt], 0, 0, 0);
        OUT[1][nt] = __builtin_amdgcn_mfma_f32_16x16x32_f16(af1, bf, OUT[1][nt], 0, 0, 0);
      }
    }
    __builtin_amdgcn_s_setprio(0);
    if (b < 7) {
      __syncthreads();  // all waves done reading wb for this b
      const ushort* gs = wg_bil + (b + 1) * 16384 + w * 4096 + lane * 8;
      ushort* ls = &wb[w * 4096];
#pragma unroll
      for (int i = 0; i < 8; i++)
        __builtin_amdgcn_global_load_lds(
            (const __attribute__((address_space(1))) void*)(gs + i * 512),
            (__attribute__((address_space(3))) void*)(ls + i * 512), 16, 0, 0);
      __syncthreads();  // staged (vmcnt drained before barrier)
    }
  }

  // scatter with in-register merge of equal-target runs (sorted order)
#pragma unroll
  for (int mt = 0; mt < 2; mt++) {
    float acc[8];
    int cte = teo[mt][0];
#pragma unroll
    for (int nt = 0; nt < 8; nt++) acc[nt] = OUT[mt][nt][0];
#pragma unroll
    for (int r = 1; r < 4; r++) {
      int nte = teo[mt][r];
      if (nte == cte) {
#pragma unroll
        for (int nt = 0; nt < 8; nt++) acc[nt] += OUT[mt][nt][r];
      } else {
        float* base = &agg[(size_t)cte * 128];
#pragma unroll
        for (int nt = 0; nt < 8; nt++)
          unsafeAtomicAdd(base + nt * 16 + r15, acc[nt]);
        cte = nte;
#pragma unroll
        for (int nt = 0; nt < 8; nt++) acc[nt] = OUT[mt][nt][r];
      }
    }
    float* base = &agg[(size_t)cte * 128];
#pragma unroll
    for (int nt = 0; nt < 8; nt++)
      unsafeAtomicAdd(base + nt * 16 + r15, acc[nt]);
  }
}

// ---------------- K4a: post layers 0..3 (10 waves, 160-row tiles) ------------
__global__ __launch_bounds__(640) void k_postA(const float* __restrict__ msg,
                                               const float* __restrict__ agg,
                                               const ushort* __restrict__ wg_lin,
                                               const float* __restrict__ bias_tab,
                                               ushort* __restrict__ xmid) {
  __shared__ ushort wb[4][16384];   // 128 KB
  __shared__ ushort sc[10][1024];   // 20 KB wave scratch
  __shared__ float bias[4][128];
  int t = threadIdx.x;
  int lane = t & 63, w = t >> 6;    // 10 waves
  int r15 = lane & 15, hi = lane >> 4;
  ushort* scw = &sc[w][0];
  const f32x4 Z4 = {0.f, 0.f, 0.f, 0.f};

  if (t < 512) {
#pragma unroll
    for (int s = 0; s < 4; s++) {
      const ushort* gs = wg_lin + (s + 1) * 16384 + t * 8;
      ushort* ls = &wb[s][t * 8];
#pragma unroll
      for (int i = 0; i < 4; i++)
        __builtin_amdgcn_global_load_lds(
            (const __attribute__((address_space(1))) void*)(gs + i * 4096),
            (__attribute__((address_space(3))) void*)(ls + i * 4096), 16, 0, 0);
    }
  }
  if (t < 128) {
#pragma unroll
    for (int s = 0; s < 4; s++) bias[s][t] = bias_tab[(s + 1) * 128 + t];
  }
  __syncthreads();  // weights staged once; no barriers after this

#pragma unroll 1
  for (int tb = blockIdx.x; tb < 1250; tb += 250) {
    int r = tb * 160 + w * 16 + r15;   // 1250*160 = 200000 exactly
    size_t gb = (size_t)r * 128;

    s16x8 st[4], mg[4];
#pragma unroll
    for (int k = 0; k < 4; k++) {
      f32x4 v0 = *(const f32x4*)&msg[gb + k * 32 + hi * 8];
      f32x4 v1 = *(const f32x4*)&msg[gb + k * 32 + hi * 8 + 4];
      u32x4 p;
      p[0] = cvtpk(v0.x, v0.y); p[1] = cvtpk(v0.z, v0.w);
      p[2] = cvtpk(v1.x, v1.y); p[3] = cvtpk(v1.z, v1.w);
      st[k] = __builtin_bit_cast(s16x8, p);
      mg[k] = st[k];
    }
    f32x4 ag[8];
#pragma unroll
    for (int nt = 0; nt < 8; nt++)
      ag[nt] = *(const f32x4*)&agg[gb + nt * 16 + hi * 4];

    f32x4 xr[8], xv[8], C[8];

    // ---- l0: x = agg + msg@Wtgt + b
#pragma unroll
    for (int k = 0; k < 4; k++)
#pragma unroll
      for (int nt = 0; nt < 8; nt++) {
        s16x8 af = *(const s16x8*)&wb[0][swz(nt * 16 + r15, k * 32 + hi * 8)];
        C[nt] = __builtin_amdgcn_mfma_f32_16x16x32_bf16(af, st[k], k == 0 ? ag[nt] : C[nt], 0, 0, 0);
      }
#pragma unroll
    for (int nt = 0; nt < 8; nt++) {
      f32x4 bv = *(const f32x4*)&bias[0][nt * 16 + hi * 4];
#pragma unroll
      for (int q = 0; q < 4; q++) xv[nt][q] = C[nt][q] + bv[q];
      xr[nt] = xv[nt];
    }
    exchCtoB(scw, r15, hi, xv, st);

    // ---- l1: h = silu(x@W1 + b)
#pragma unroll
    for (int k = 0; k < 4; k++)
#pragma unroll
      for (int nt = 0; nt < 8; nt++) {
        s16x8 af = *(const s16x8*)&wb[1][swz(nt * 16 + r15, k * 32 + hi * 8)];
        C[nt] = __builtin_amdgcn_mfma_f32_16x16x32_bf16(af, st[k], k == 0 ? Z4 : C[nt], 0, 0, 0);
      }
#pragma unroll
    for (int nt = 0; nt < 8; nt++) {
      f32x4 bv = *(const f32x4*)&bias[1][nt * 16 + hi * 4];
#pragma unroll
      for (int q = 0; q < 4; q++) xv[nt][q] = silu_f(C[nt][q] + bv[q]);
    }
    exchCtoB(scw, r15, hi, xv, st);

    // ---- l2: x = x + silu(h@W2 + b)
#pragma unroll
    for (int k = 0; k < 4; k++)
#pragma unroll
      for (int nt = 0; nt < 8; nt++) {
        s16x8 af = *(const s16x8*)&wb[2][swz(nt * 16 + r15, k * 32 + hi * 8)];
        C[nt] = __builtin_amdgcn_mfma_f32_16x16x32_bf16(af, st[k], k == 0 ? Z4 : C[nt], 0, 0, 0);
      }
#pragma unroll
    for (int nt = 0; nt < 8; nt++) {
      f32x4 bv = *(const f32x4*)&bias[2][nt * 16 + hi * 4];
#pragma unroll
      for (int q = 0; q < 4; q++) xv[nt][q] = xr[nt][q] + silu_f(C[nt][q] + bv[q]);
    }
    exchCtoB(scw, r15, hi, xv, st);

    // ---- l3: x = silu(x@Wskip + b) + msg; store bf16
#pragma unroll
    for (int k = 0; k < 4; k++)
#pragma unroll
      for (int nt = 0; nt < 8; nt++) {
        s16x8 af = *(const s16x8*)&wb[3][swz(nt * 16 + r15, k * 32 + hi * 8)];
        C[nt] = __builtin_amdgcn_mfma_f32_16x16x32_bf16(af, st[k], k == 0 ? Z4 : C[nt], 0, 0, 0);
      }
    u32x2 mc[8];
    exchBtoC(scw, r15, hi, mg, mc);
#pragma unroll
    for (int nt = 0; nt < 8; nt++) {
      f32x4 bv = *(const f32x4*)&bias[3][nt * 16 + hi * 4];
      f32x4 m0;
      m0[0] = __uint_as_float(mc[nt][0] << 16);
      m0[1] = __uint_as_float(mc[nt][0] & 0xffff0000u);
      m0[2] = __uint_as_float(mc[nt][1] << 16);
      m0[3] = __uint_as_float(mc[nt][1] & 0xffff0000u);
      u32x2 pk;
      float o0 = silu_f(C[nt][0] + bv[0]) + m0[0];
      float o1 = silu_f(C[nt][1] + bv[1]) + m0[1];
      float o2 = silu_f(C[nt][2] + bv[2]) + m0[2];
      float o3 = silu_f(C[nt][3] + bv[3]) + m0[3];
      pk[0] = cvtpk(o0, o1);
      pk[1] = cvtpk(o2, o3);
      *(u32x2*)&xmid[gb + nt * 16 + hi * 4] = pk;
    }
  }
}

// ---------------- K4b: post layers 4..7 (10 waves, 160-row tiles) ------------
__global__ __launch_bounds__(640) void k_postB(const ushort* __restrict__ xmid,
                                               const ushort* __restrict__ wg_lin,
                                               const float* __restrict__ bias_tab,
                                               float* __restrict__ xout) {
  __shared__ ushort wb[4][16384];
  __shared__ ushort sc[10][1024];
  __shared__ float bias[4][128];
  int t = threadIdx.x;
  int lane = t & 63, w = t >> 6;
  int r15 = lane & 15, hi = lane >> 4;
  ushort* scw = &sc[w][0];
  const f32x4 Z4 = {0.f, 0.f, 0.f, 0.f};

  if (t < 512) {
#pragma unroll
    for (int s = 0; s < 4; s++) {
      const ushort* gs = wg_lin + (s + 5) * 16384 + t * 8;
      ushort* ls = &wb[s][t * 8];
#pragma unroll
      for (int i = 0; i < 4; i++)
        __builtin_amdgcn_global_load_lds(
            (const __attribute__((address_space(1))) void*)(gs + i * 4096),
            (__attribute__((address_space(3))) void*)(ls + i * 4096), 16, 0, 0);
    }
  }
  if (t < 128) {
#pragma unroll
    for (int s = 0; s < 4; s++) bias[s][t] = bias_tab[(s + 5) * 128 + t];
  }
  __syncthreads();

#pragma unroll 1
  for (int tb = blockIdx.x; tb < 1250; tb += 250) {
    int r = tb * 160 + w * 16 + r15;
    size_t gb = (size_t)r * 128;

    s16x8 st[4];
#pragma unroll
    for (int k = 0; k < 4; k++)
      st[k] = *(const s16x8*)&xmid[gb + k * 32 + hi * 8];
    u32x2 mc[8];
    exchBtoC(scw, r15, hi, st, mc);
    f32x4 xr[8], xv[8], C[8];
#pragma unroll
    for (int nt = 0; nt < 8; nt++) {
      xr[nt][0] = __uint_as_float(mc[nt][0] << 16);
      xr[nt][1] = __uint_as_float(mc[nt][0] & 0xffff0000u);
      xr[nt][2] = __uint_as_float(mc[nt][1] << 16);
      xr[nt][3] = __uint_as_float(mc[nt][1] & 0xffff0000u);
    }

    // ---- l4
#pragma unroll
    for (int k = 0; k < 4; k++)
#pragma unroll
      for (int nt = 0; nt < 8; nt++) {
        s16x8 af = *(const s16x8*)&wb[0][swz(nt * 16 + r15, k * 32 + hi * 8)];
        C[nt] = __builtin_amdgcn_mfma_f32_16x16x32_bf16(af, st[k], k == 0 ? Z4 : C[nt], 0, 0, 0);
      }
#pragma unroll
    for (int nt = 0; nt < 8; nt++) {
      f32x4 bv = *(const f32x4*)&bias[0][nt * 16 + hi * 4];
#pragma unroll
      for (int q = 0; q < 4; q++) xv[nt][q] = silu_f(C[nt][q] + bv[q]);
    }
    exchCtoB(scw, r15, hi, xv, st);

    // ---- l5
#pragma unroll
    for (int k = 0; k < 4; k++)
#pragma unroll
      for (int nt = 0; nt < 8; nt++) {
        s16x8 af = *(const s16x8*)&wb[1][swz(nt * 16 + r15, k * 32 + hi * 8)];
        C[nt] = __builtin_amdgcn_mfma_f32_16x16x32_bf16(af, st[k], k == 0 ? Z4 : C[nt], 0, 0, 0);
      }
#pragma unroll
    for (int nt = 0; nt < 8; nt++) {
      f32x4 bv = *(const f32x4*)&bias[1][nt * 16 + hi * 4];
#pragma unroll
      for (int q = 0; q < 4; q++) xv[nt][q] = xr[nt][q] + silu_f(C[nt][q] + bv[q]);
      xr[nt] = xv[nt];
    }
    exchCtoB(scw, r15, hi, xv, st);

    // ---- l6
#pragma unroll
    for (int k = 0; k < 4; k++)
#pragma unroll
      for (int nt = 0; nt < 8; nt++) {
        s16x8 af = *(const s16x8*)&wb[2][swz(nt * 16 + r15, k * 32 + hi * 8)];
        C[nt] = __builtin_amdgcn_mfma_f32_16x16x32_bf16(af, st[k], k == 0 ? Z4 : C[nt], 0, 0, 0);
      }
#pragma unroll
    for (int nt = 0; nt < 8; nt++) {
      f32x4 bv = *(const f32x4*)&bias[2][nt * 16 + hi * 4];
#pragma unroll
      for (int q = 0; q < 4; q++) xv[nt][q] = silu_f(C[nt][q] + bv[q]);
    }
    exchCtoB(scw, r15, hi, xv, st);

    // ---- l7
#pragma unroll
    for (int k = 0; k < 4; k++)
#pragma unroll
      for (int nt = 0; nt < 8; nt++) {
        s16x8 af = *(const s16x8*)&wb[3][swz(nt * 16 + r15, k * 32 + hi * 8)];
        C[nt] = __builtin_amdgcn_mfma_f32_16x16x32_bf16(af, st[k], k == 0 ? Z4 : C[nt], 0, 0, 0);
      }
#pragma unroll
    for (int nt = 0; nt < 8; nt++) {
      f32x4 bv = *(const f32x4*)&bias[3][nt * 16 + hi * 4];
      f32x4 o;
#pragma unroll
      for (int q = 0; q < 4; q++) o[q] = xr[nt][q] + silu_f(C[nt][q] + bv[q]);
      *(f32x4*)&xout[gb + nt * 16 + hi * 4] = o;
    }
  }
}

extern "C" void kernel_launch(void* const* d_in, const int* in_sizes, int n_in,
                              void* d_out, int out_size, void* d_ws, size_t ws_size,
                              hipStream_t stream) {
  const float* dist  = (const float*)d_in[0];
  const float* ang   = (const float*)d_in[1];
  const float* msg   = (const float*)d_in[2];
  const int*   aidx  = (const int*)d_in[3];
  const float* Wd    = (const float*)d_in[4];
  const float* Wang  = (const float*)d_in[5];
  const float* Wsrc  = (const float*)d_in[6];
  const float* bsrc  = (const float*)d_in[7];
  const float* Wtgt  = (const float*)d_in[8];
  const float* btgt  = (const float*)d_in[9];
  const float* Wbil  = (const float*)d_in[10];
  const float* WresB = (const float*)d_in[11];
  const float* bresB = (const float*)d_in[12];
  const float* Wskip = (const float*)d_in[13];
  const float* bskip = (const float*)d_in[14];
  const float* WresA = (const float*)d_in[15];
  const float* bresA = (const float*)d_in[16];

  char* ws = (char*)d_ws;
  ushort* srcm_f16 = (ushort*)(ws + 0);
  ushort* dtab_f16 = (ushort*)(ws + 51200000LL);
  float*  a_ws     = (float*)(ws + 102400000LL);
  ushort* wg_bil   = (ushort*)(ws + 134400000LL);
  ushort* wg_lin   = (ushort*)(ws + 134662144LL);
  float*  bias_tab = (float*)(ws + 134957056LL);
  int*    cnt      = (int*)(ws + 134961664LL);
  int*    cursor   = (int*)(ws + 135761664LL);
  int*    excl     = (int*)(ws + 136561664LL);
  int*    bsum     = (int*)(ws + 137361664LL);
  int*    ste      = (int*)(ws + 141362688LL);
  ushort* xmid     = (ushort*)(ws + 145362688LL);
  int*    sse      = (int*)(ws + 196562688LL);
  u32x4*  a_srt    = (u32x4*)(ws + 200562688LL);
  float*  agg      = (float*)d_out;

  (void)in_sizes; (void)n_in; (void)out_size; (void)ws_size;

  const int NSCAN = (E_N + 1023) / 1024;  // 196

  hipMemsetAsync(d_out, 0, (size_t)E_N * 128 * 4, stream);
  hipMemsetAsync(cnt, 0, (size_t)E_N * 4, stream);
  k_prep<<<1093, 256, 0, stream>>>(Wbil, Wsrc, Wtgt, WresB, Wskip, WresA,
                                   bsrc, btgt, bresB, bskip, bresA,
                                   wg_bil, wg_lin, bias_tab);
  k_angle<<<7813, 256, 0, stream>>>(ang, Wang, a_ws);
  k_hist<<<3907, 256, 0, stream>>>(aidx, cnt);
  k_scan1<<<NSCAN, 256, 0, stream>>>(cnt, excl, bsum);
  k_scan2<<<1, 256, 0, stream>>>(bsum, NSCAN);
  k_scan3<<<NSCAN, 256, 0, stream>>>(excl, bsum, cursor);
  k_scatter<<<3907, 256, 0, stream>>>(aidx, cursor, a_ws, ste, sse, a_srt);
  k_dist<<<3125, 256, 0, stream>>>(dist, Wd, dtab_f16);
  k_srcm<<<1563, 512, 0, stream>>>(msg, wg_lin, bias_tab, srcm_f16);
  k_bil<<<7813, 256, 0, stream>>>(sse, srcm_f16, dtab_f16, a_srt, wg_bil,
                                  ste, agg);
  k_postA<<<250, 640, 0, stream>>>(msg, agg, wg_lin, bias_tab, xmid);
  k_postB<<<250, 640, 0, stream>>>(xmid, wg_lin, bias_tab, (float*)d_out);
}

// Round 18
// 772.488 us; speedup vs baseline: 1.0169x; 1.0169x over previous
//
#include <hip/hip_runtime.h>
#include <hip/hip_fp16.h>
#include <stdint.h>

#define E_N 200000
#define A_N 1000000

typedef short s16x8 __attribute__((ext_vector_type(8)));
typedef short s16x4 __attribute__((ext_vector_type(4)));
typedef float f32x4 __attribute__((ext_vector_type(4)));
typedef uint32_t u32x4 __attribute__((ext_vector_type(4)));
typedef uint32_t u32x2 __attribute__((ext_vector_type(2)));
typedef int i32x4 __attribute__((ext_vector_type(4)));
typedef _Float16 f16x8 __attribute__((ext_vector_type(8)));

__device__ __forceinline__ ushort f2bf(float f) {
  uint32_t x = __float_as_uint(f);
  uint32_t r = x + 0x7FFFu + ((x >> 16) & 1u);
  return (ushort)(r >> 16);
}

__device__ __forceinline__ ushort f2h(float f) {
  return __half_as_ushort(__float2half(f));
}

__device__ __forceinline__ uint32_t cvtpk(float lo, float hi) {
  uint32_t r;
  asm("v_cvt_pk_bf16_f32 %0, %1, %2" : "=v"(r) : "v"(lo), "v"(hi));
  return r;
}

__device__ __forceinline__ uint32_t pkmul(uint32_t a, uint32_t b) {
  uint32_t r;
  asm("v_pk_mul_f16 %0, %1, %2" : "=v"(r) : "v"(a), "v"(b));
  return r;
}

__device__ __forceinline__ float silu_f(float v) {
  return v * (1.0f / (1.0f + __expf(-v)));
}

// swizzled element offset within a [rows][128] 16-bit tile (XOR bank-swizzle)
__device__ __forceinline__ int swz(int row, int h) {
  return row * 128 + (h ^ ((row & 7) << 3));
}

// element offset in a 2KB per-wave scratch: 16 rows x 64 cols (col mod 64)
__device__ __forceinline__ int sws(int r, int c) {
  return r * 64 + ((c & 63) ^ ((r & 7) << 3));
}

// C-layout f32 -> B-frags via 2 half-passes through 2KB wave scratch.
__device__ __forceinline__ void exchCtoB(ushort* scw, int r15, int hi,
                                         const f32x4* xv, s16x8* st) {
  u32x2 pk[8];
#pragma unroll
  for (int nt = 0; nt < 8; nt++) {
    pk[nt][0] = cvtpk(xv[nt][0], xv[nt][1]);
    pk[nt][1] = cvtpk(xv[nt][2], xv[nt][3]);
  }
#pragma unroll
  for (int nt = 0; nt < 4; nt++)
    *(u32x2*)&scw[sws(r15, nt * 16 + hi * 4)] = pk[nt];
#pragma unroll
  for (int k = 0; k < 2; k++)
    st[k] = *(const s16x8*)&scw[sws(r15, k * 32 + hi * 8)];
#pragma unroll
  for (int nt = 4; nt < 8; nt++)
    *(u32x2*)&scw[sws(r15, nt * 16 + hi * 4)] = pk[nt];
#pragma unroll
  for (int k = 2; k < 4; k++)
    st[k] = *(const s16x8*)&scw[sws(r15, k * 32 + hi * 8)];
}

// B-frags -> C-layout bf16 pairs
__device__ __forceinline__ void exchBtoC(ushort* scw, int r15, int hi,
                                         const s16x8* stv, u32x2* mc) {
#pragma unroll
  for (int k = 0; k < 2; k++)
    *(s16x8*)&scw[sws(r15, k * 32 + hi * 8)] = stv[k];
#pragma unroll
  for (int nt = 0; nt < 4; nt++)
    mc[nt] = *(const u32x2*)&scw[sws(r15, nt * 16 + hi * 4)];
#pragma unroll
  for (int k = 2; k < 4; k++)
    *(s16x8*)&scw[sws(r15, k * 32 + hi * 8)] = stv[k];
#pragma unroll
  for (int nt = 4; nt < 8; nt++)
    mc[nt] = *(const u32x2*)&scw[sws(r15, nt * 16 + hi * 4)];
}

// ---------------- prep: wg_bil -> f16; wg_lin -> bf16; transposed, swizzled --
__global__ __launch_bounds__(256) void k_prep(
    const float* __restrict__ Wbil, const float* __restrict__ Wsrc,
    const float* __restrict__ Wtgt, const float* __restrict__ WresB,
    const float* __restrict__ Wskip, const float* __restrict__ WresA,
    const float* __restrict__ bsrc, const float* __restrict__ btgt,
    const float* __restrict__ bresB, const float* __restrict__ bskip,
    const float* __restrict__ bresA,
    ushort* __restrict__ wg_bil, ushort* __restrict__ wg_lin,
    float* __restrict__ bias_tab) {
  int tid = blockIdx.x * 256 + threadIdx.x;
  if (tid < 8 * 16384) {
    int b = tid >> 14, r = tid & 16383;
    int i = r >> 7, h = r & 127;
    wg_bil[b * 16384 + swz(i, h)] = f2h(Wbil[(i * 8 + b) * 128 + h]);
    return;
  }
  tid -= 8 * 16384;
  if (tid < 9 * 16384) {
    int s = tid >> 14, r = tid & 16383;
    int c = r >> 7, h = r & 127;
    const float* src;
    switch (s) {
      case 0: src = Wsrc; break;
      case 1: src = Wtgt; break;
      case 2: src = WresB; break;
      case 3: src = WresB + 16384; break;
      case 4: src = Wskip; break;
      case 5: src = WresA; break;
      case 6: src = WresA + 16384; break;
      case 7: src = WresA + 32768; break;
      default: src = WresA + 49152; break;
    }
    wg_lin[s * 16384 + swz(c, h)] = f2bf(src[h * 128 + c]);
    return;
  }
  tid -= 9 * 16384;
  if (tid < 9 * 128) {
    int s = tid >> 7, c = tid & 127;
    const float* src;
    switch (s) {
      case 0: src = bsrc; break;
      case 1: src = btgt; break;
      case 2: src = bresB; break;
      case 3: src = bresB + 128; break;
      case 4: src = bskip; break;
      case 5: src = bresA; break;
      case 6: src = bresA + 128; break;
      case 7: src = bresA + 256; break;
      default: src = bresA + 384; break;
    }
    bias_tab[s * 128 + c] = src[c];
  }
}

// ---------------- sort-by-target infrastructure ------------------------------
__global__ __launch_bounds__(256) void k_hist(const int* __restrict__ aidx,
                                              int* __restrict__ cnt) {
  int i = blockIdx.x * 256 + threadIdx.x;
  if (i < A_N) atomicAdd(&cnt[aidx[A_N + i]], 1);
}

__global__ __launch_bounds__(256) void k_scan1(const int* __restrict__ cnt,
                                               int* __restrict__ excl,
                                               int* __restrict__ bsum) {
  __shared__ int s[256];
  int t = threadIdx.x;
  int base = blockIdx.x * 1024 + t * 4;
  int v[4];
#pragma unroll
  for (int j = 0; j < 4; j++) v[j] = (base + j < E_N) ? cnt[base + j] : 0;
  int sum = v[0] + v[1] + v[2] + v[3];
  s[t] = sum;
  __syncthreads();
#pragma unroll
  for (int d = 1; d < 256; d <<= 1) {
    int x = (t >= d) ? s[t - d] : 0;
    __syncthreads();
    s[t] += x;
    __syncthreads();
  }
  int run = s[t] - sum;
#pragma unroll
  for (int j = 0; j < 4; j++) {
    if (base + j < E_N) excl[base + j] = run;
    run += v[j];
  }
  if (t == 255) bsum[blockIdx.x] = s[255];
}

__global__ __launch_bounds__(256) void k_scan2(int* __restrict__ bsum, int nb) {
  __shared__ int s[256];
  int t = threadIdx.x;
  int orig = (t < nb) ? bsum[t] : 0;
  s[t] = orig;
  __syncthreads();
#pragma unroll
  for (int d = 1; d < 256; d <<= 1) {
    int x = (t >= d) ? s[t - d] : 0;
    __syncthreads();
    s[t] += x;
    __syncthreads();
  }
  if (t < nb) bsum[t] = s[t] - orig;
}

__global__ __launch_bounds__(256) void k_scan3(const int* __restrict__ excl,
                                               const int* __restrict__ bsum,
                                               int* __restrict__ cursor) {
  int t = threadIdx.x;
  int base = blockIdx.x * 1024 + t * 4;
  int add = bsum[blockIdx.x];
#pragma unroll
  for (int j = 0; j < 4; j++)
    if (base + j < E_N) cursor[base + j] = excl[base + j] + add;
}

// scatter + fused a-conversion: writes sorted te/se and pre-converted
// duplicated-f16 a pairs at the sorted position.
__global__ __launch_bounds__(256) void k_scatter(const int* __restrict__ aidx,
                                                 int* __restrict__ cursor,
                                                 const float* __restrict__ a_ws,
                                                 int* __restrict__ ste,
                                                 int* __restrict__ sse,
                                                 u32x4* __restrict__ a_srt) {
  int i = blockIdx.x * 256 + threadIdx.x;
  if (i < A_N) {
    int te = aidx[A_N + i];
    int se = aidx[i];
    int pos = atomicAdd(&cursor[te], 1);
    ste[pos] = te;
    sse[pos] = se;
    f32x4 a0 = *(const f32x4*)&a_ws[(size_t)i * 8];
    f32x4 a1 = *(const f32x4*)&a_ws[(size_t)i * 8 + 4];
    u32x4 o0, o1;
#pragma unroll
    for (int j = 0; j < 4; j++) {
      uint32_t h0 = f2h(a0[j]), h1 = f2h(a1[j]);
      o0[j] = (h0 << 16) | h0;
      o1[j] = (h1 << 16) | h1;
    }
    a_srt[(size_t)pos * 2] = o0;
    a_srt[(size_t)pos * 2 + 1] = o1;
  }
}

// ---------------- K1: a = angle.reshape(A,42) @ W_angle  -> [A,8] f32 --------
__global__ __launch_bounds__(256) void k_angle(const float* __restrict__ ang,
                                               const float* __restrict__ Wang,
                                               float* __restrict__ a_ws) {
  __shared__ float rows[128 * 42];
  __shared__ float wbuf[42 * 8];
  int t = threadIdx.x;
  int tile0 = blockIdx.x * 128;
  int nrows = A_N - tile0; if (nrows > 128) nrows = 128;
  if (nrows == 128) {
    const f32x4* src = (const f32x4*)(ang + (size_t)tile0 * 42);
    f32x4* dst = (f32x4*)rows;
    for (int k = t; k < 1344; k += 256) dst[k] = src[k];
  } else {
    int cnt = nrows * 42;
    for (int k = t; k < cnt; k += 256) rows[k] = ang[(size_t)tile0 * 42 + k];
  }
  for (int k = t; k < 336; k += 256) wbuf[k] = Wang[k];
  __syncthreads();
  int row = t >> 1, half = t & 1;
  if (row < nrows) {
    float a0 = 0.f, a1 = 0.f, a2 = 0.f, a3 = 0.f;
    const float* rp = &rows[row * 42];
    const float* wp = &wbuf[half * 4];
#pragma unroll
    for (int k = 0; k < 42; k++) {
      float v = rp[k];
      a0 += v * wp[k * 8 + 0]; a1 += v * wp[k * 8 + 1];
      a2 += v * wp[k * 8 + 2]; a3 += v * wp[k * 8 + 3];
    }
    f32x4 o; o.x = a0; o.y = a1; o.z = a2; o.w = a3;
    *(f32x4*)&a_ws[(tile0 + row) * 8 + half * 4] = o;
  }
}

// ---------------- Kd: d = dist @ W_dist  -> [E,128] f16 ----------------------
__global__ __launch_bounds__(256) void k_dist(const float* __restrict__ dist,
                                              const float* __restrict__ Wd,
                                              ushort* __restrict__ dtab) {
  __shared__ float w[6 * 128];
  int t = threadIdx.x;
  for (int k = t; k < 768; k += 256) w[k] = Wd[k];
  __syncthreads();
  int gid = blockIdx.x * 256 + t;
  int e = gid >> 2, q = gid & 3;
  if (e >= E_N) return;
  float dv[6];
#pragma unroll
  for (int r = 0; r < 6; r++) dv[r] = dist[e * 6 + r];
#pragma unroll
  for (int j = 0; j < 32; j += 4) {
    int c = q * 32 + j;
    s16x4 o;
#pragma unroll
    for (int jj = 0; jj < 4; jj++) {
      float s = 0.f;
#pragma unroll
      for (int r = 0; r < 6; r++) s += dv[r] * w[r * 128 + c + jj];
      o[jj] = (short)f2h(s);
    }
    *(s16x4*)&dtab[e * 128 + c] = o;
  }
}

// ---------------- K2: srcm = message @ W_src + b_src (bf16 MFMA) -> f16 ------
__global__ __launch_bounds__(512) void k_srcm(const float* __restrict__ msg,
                                              const ushort* __restrict__ wg_lin,
                                              const float* __restrict__ bias_tab,
                                              ushort* __restrict__ srcm) {
  __shared__ ushort xb[128 * 128];
  __shared__ ushort wb[16384];
  __shared__ float bias[128];
  int t = threadIdx.x;
  int tile0 = blockIdx.x * 128;
  const f32x4 Z4 = {0.f, 0.f, 0.f, 0.f};
  for (int off = t * 8; off < 16384; off += 4096)
    *(s16x8*)&wb[off] = *(const s16x8*)&wg_lin[off];
  if (t < 128) bias[t] = bias_tab[t];
  {
    int row = t >> 2, l = t & 3;
    int grow = tile0 + row;
#pragma unroll
    for (int j = 0; j < 8; j++) {
      int h = l * 32 + j * 4;
      s16x4 o; o[0] = 0; o[1] = 0; o[2] = 0; o[3] = 0;
      if (grow < E_N) {
        f32x4 v = *(const f32x4*)&msg[(size_t)grow * 128 + h];
        o[0] = (short)f2bf(v.x); o[1] = (short)f2bf(v.y);
        o[2] = (short)f2bf(v.z); o[3] = (short)f2bf(v.w);
      }
      *(s16x4*)&xb[swz(row, h)] = o;
    }
  }
  __syncthreads();
  int w = t >> 6, lane = t & 63;
  int rbase = w * 16;
  int arow = rbase + (lane & 15);
  int k0 = (lane >> 4) * 8;
  int r0 = (lane >> 4) * 4;
  f32x4 acc[8];
#pragma unroll
  for (int k = 0; k < 4; k++) {
    s16x8 af = *(const s16x8*)&xb[swz(arow, k * 32 + k0)];
#pragma unroll
    for (int nt = 0; nt < 8; nt++) {
      s16x8 bf = *(const s16x8*)&wb[swz(nt * 16 + (lane & 15), k * 32 + k0)];
      acc[nt] = __builtin_amdgcn_mfma_f32_16x16x32_bf16(af, bf, k == 0 ? Z4 : acc[nt], 0, 0, 0);
    }
  }
#pragma unroll
  for (int nt = 0; nt < 8; nt++) {
    int col = nt * 16 + (lane & 15);
    float bv = bias[col];
#pragma unroll
    for (int r = 0; r < 4; r++) {
      int grow = tile0 + rbase + r0 + r;
      if (grow < E_N) srcm[(size_t)grow * 128 + col] = f2h(acc[nt][r] + bv);
    }
  }
}

// ---------------- K3: sorted gather + bilinear f16 MFMA, 1-buffer, 3 blk/CU --
__global__ __launch_bounds__(256, 3) void k_bil(const int* __restrict__ sse,
                                                const ushort* __restrict__ srcm,
                                                const ushort* __restrict__ dtab,
                                                const u32x4* __restrict__ a_srt,
                                                const ushort* __restrict__ wg_bil,
                                                const int* __restrict__ ste,
                                                float* __restrict__ agg) {
  __shared__ ushort wb[16384];   // 32 KB single buffer (f16, pre-swizzled)
  int t = threadIdx.x;
  int lane = t & 63, w = t >> 6;
  int tile0 = blockIdx.x * 128;
  int mb = w * 32;
  int r15 = lane & 15, hi = lane >> 4;
  int k0 = hi * 8;
  int r0 = hi * 4;
  const f32x4 Z4 = {0.f, 0.f, 0.f, 0.f};

  // stage b=0
  {
    const ushort* gs = wg_bil + w * 4096 + lane * 8;
    ushort* ls = &wb[w * 4096];
#pragma unroll
    for (int i = 0; i < 8; i++)
      __builtin_amdgcn_global_load_lds(
          (const __attribute__((address_space(1))) void*)(gs + i * 512),
          (__attribute__((address_space(3))) void*)(ls + i * 512), 16, 0, 0);
  }

  // gather sm = srcm[src]*d[tgt] in PACKED f16; all index loads coalesced
  u32x4 smv[2][4];      // [mt][k]: 4 u32 = 8 f16
  uint32_t avd[2][8];   // a_b duplicated f16 pairs (pre-converted)
  int teo[2][4];
#pragma unroll
  for (int mt = 0; mt < 2; mt++) {
    int grow = tile0 + mb + mt * 16 + r15;
    int ok = (grow < A_N);
    int se = ok ? sse[grow] : 0;
    int te = ok ? ste[grow] : 0;
    if (ok) {
      u32x4 o0 = a_srt[(size_t)grow * 2];
      u32x4 o1 = a_srt[(size_t)grow * 2 + 1];
#pragma unroll
      for (int j = 0; j < 4; j++) { avd[mt][j] = o0[j]; avd[mt][4 + j] = o1[j]; }
    } else {
#pragma unroll
      for (int j = 0; j < 8; j++) avd[mt][j] = 0u;
    }
#pragma unroll
    for (int k = 0; k < 4; k++) {
      u32x4 sv = *(const u32x4*)&srcm[(size_t)se * 128 + k * 32 + k0];
      u32x4 dv = *(const u32x4*)&dtab[(size_t)te * 128 + k * 32 + k0];
#pragma unroll
      for (int j = 0; j < 4; j++) smv[mt][k][j] = pkmul(sv[j], dv[j]);
    }
    int orow0 = tile0 + mb + mt * 16 + r0;
    if (orow0 + 3 < A_N) {
      i32x4 tq = *(const i32x4*)&ste[orow0];
#pragma unroll
      for (int r = 0; r < 4; r++) teo[mt][r] = tq[r];
    } else {
#pragma unroll
      for (int r = 0; r < 4; r++)
        teo[mt][r] = (orow0 + r < A_N) ? ste[orow0 + r] : 0;
    }
  }

  f32x4 OUT[2][8];
#pragma unroll
  for (int mt = 0; mt < 2; mt++)
#pragma unroll
    for (int nt = 0; nt < 8; nt++) OUT[mt][nt] = Z4;

  __syncthreads();  // b=0 staged

#pragma unroll
  for (int b = 0; b < 8; b++) {
    uint32_t a0b = avd[0][b], a1b = avd[1][b];
    __builtin_amdgcn_s_setprio(1);
#pragma unroll
    for (int k = 0; k < 4; k++) {
      u32x4 p0, p1;
#pragma unroll
      for (int j = 0; j < 4; j++) {
        p0[j] = pkmul(smv[0][k][j], a0b);
        p1[j] = pkmul(smv[1][k][j], a1b);
      }
      f16x8 af0 = __builtin_bit_cast(f16x8, p0);
      f16x8 af1 = __builtin_bit_cast(f16x8, p1);
#pragma unroll
      for (int nt = 0; nt < 8; nt++) {
        f16x8 bf = *(const f16x8*)&wb[swz(nt * 16 + r15, k * 32 + k0)];
        OUT[0][nt] = __builtin_amdgcn_mfma_f32_16x16x32_f16(af0, bf, OUT[0][nt], 0, 0, 0);
        OUT[1][nt] = __builtin_amdgcn_mfma_f32_16x16x32_f16(af1, bf, OUT[1][nt], 0, 0, 0);
      }
    }
    __builtin_amdgcn_s_setprio(0);
    if (b < 7) {
      __syncthreads();  // all waves done reading wb for this b
      const ushort* gs = wg_bil + (b + 1) * 16384 + w * 4096 + lane * 8;
      ushort* ls = &wb[w * 4096];
#pragma unroll
      for (int i = 0; i < 8; i++)
        __builtin_amdgcn_global_load_lds(
            (const __attribute__((address_space(1))) void*)(gs + i * 512),
            (__attribute__((address_space(3))) void*)(ls + i * 512), 16, 0, 0);
      __syncthreads();  // staged (vmcnt drained before barrier)
    }
  }

  // scatter with in-register merge of equal-target runs (sorted order)
#pragma unroll
  for (int mt = 0; mt < 2; mt++) {
    float acc[8];
    int cte = teo[mt][0];
#pragma unroll
    for (int nt = 0; nt < 8; nt++) acc[nt] = OUT[mt][nt][0];
#pragma unroll
    for (int r = 1; r < 4; r++) {
      int nte = teo[mt][r];
      if (nte == cte) {
#pragma unroll
        for (int nt = 0; nt < 8; nt++) acc[nt] += OUT[mt][nt][r];
      } else {
        float* base = &agg[(size_t)cte * 128];
#pragma unroll
        for (int nt = 0; nt < 8; nt++)
          unsafeAtomicAdd(base + nt * 16 + r15, acc[nt]);
        cte = nte;
#pragma unroll
        for (int nt = 0; nt < 8; nt++) acc[nt] = OUT[mt][nt][r];
      }
    }
    float* base = &agg[(size_t)cte * 128];
#pragma unroll
    for (int nt = 0; nt < 8; nt++)
      unsafeAtomicAdd(base + nt * 16 + r15, acc[nt]);
  }
}

// ---------------- K4a: post layers 0..3 (1 blk/CU; grid=256 balanced) --------
__global__ __launch_bounds__(512) void k_postA(const float* __restrict__ msg,
                                               const float* __restrict__ agg,
                                               const ushort* __restrict__ wg_lin,
                                               const float* __restrict__ bias_tab,
                                               ushort* __restrict__ xmid) {
  __shared__ ushort wb[4][16384];   // 128 KB
  __shared__ ushort sc[8][1024];    // 16 KB wave scratch
  __shared__ float bias[4][128];
  int t = threadIdx.x;
  int lane = t & 63, w = t >> 6;
  int r15 = lane & 15, hi = lane >> 4;
  ushort* scw = &sc[w][0];
  const f32x4 Z4 = {0.f, 0.f, 0.f, 0.f};

#pragma unroll
  for (int s = 0; s < 4; s++) {
    const ushort* gs = wg_lin + (s + 1) * 16384 + t * 8;
    ushort* ls = &wb[s][t * 8];
#pragma unroll
    for (int i = 0; i < 4; i++)
      __builtin_amdgcn_global_load_lds(
          (const __attribute__((address_space(1))) void*)(gs + i * 4096),
          (__attribute__((address_space(3))) void*)(ls + i * 4096), 16, 0, 0);
  }
  if (t < 128) {
#pragma unroll
    for (int s = 0; s < 4; s++) bias[s][t] = bias_tab[(s + 1) * 128 + t];
  }
  __syncthreads();  // weights staged once; no barriers after this

#pragma unroll 1
  for (int tb = blockIdx.x; tb < 1563; tb += 256) {
    int r = tb * 128 + w * 16 + r15;
    bool ok = r < E_N;
    size_t gb = (size_t)r * 128;

    s16x8 st[4], mg[4];
#pragma unroll
    for (int k = 0; k < 4; k++) {
      f32x4 v0 = Z4, v1 = Z4;
      if (ok) {
        v0 = *(const f32x4*)&msg[gb + k * 32 + hi * 8];
        v1 = *(const f32x4*)&msg[gb + k * 32 + hi * 8 + 4];
      }
      u32x4 p;
      p[0] = cvtpk(v0.x, v0.y); p[1] = cvtpk(v0.z, v0.w);
      p[2] = cvtpk(v1.x, v1.y); p[3] = cvtpk(v1.z, v1.w);
      st[k] = __builtin_bit_cast(s16x8, p);
      mg[k] = st[k];
    }
    f32x4 ag[8];
#pragma unroll
    for (int nt = 0; nt < 8; nt++)
      ag[nt] = ok ? *(const f32x4*)&agg[gb + nt * 16 + hi * 4] : Z4;

    f32x4 xr[8], xv[8], C[8];

    // ---- l0: x = agg + msg@Wtgt + b
#pragma unroll
    for (int k = 0; k < 4; k++)
#pragma unroll
      for (int nt = 0; nt < 8; nt++) {
        s16x8 af = *(const s16x8*)&wb[0][swz(nt * 16 + r15, k * 32 + hi * 8)];
        C[nt] = __builtin_amdgcn_mfma_f32_16x16x32_bf16(af, st[k], k == 0 ? ag[nt] : C[nt], 0, 0, 0);
      }
#pragma unroll
    for (int nt = 0; nt < 8; nt++) {
      f32x4 bv = *(const f32x4*)&bias[0][nt * 16 + hi * 4];
#pragma unroll
      for (int q = 0; q < 4; q++) xv[nt][q] = C[nt][q] + bv[q];
      xr[nt] = xv[nt];
    }
    exchCtoB(scw, r15, hi, xv, st);

    // ---- l1: h = silu(x@W1 + b)
#pragma unroll
    for (int k = 0; k < 4; k++)
#pragma unroll
      for (int nt = 0; nt < 8; nt++) {
        s16x8 af = *(const s16x8*)&wb[1][swz(nt * 16 + r15, k * 32 + hi * 8)];
        C[nt] = __builtin_amdgcn_mfma_f32_16x16x32_bf16(af, st[k], k == 0 ? Z4 : C[nt], 0, 0, 0);
      }
#pragma unroll
    for (int nt = 0; nt < 8; nt++) {
      f32x4 bv = *(const f32x4*)&bias[1][nt * 16 + hi * 4];
#pragma unroll
      for (int q = 0; q < 4; q++) xv[nt][q] = silu_f(C[nt][q] + bv[q]);
    }
    exchCtoB(scw, r15, hi, xv, st);

    // ---- l2: x = x + silu(h@W2 + b)
#pragma unroll
    for (int k = 0; k < 4; k++)
#pragma unroll
      for (int nt = 0; nt < 8; nt++) {
        s16x8 af = *(const s16x8*)&wb[2][swz(nt * 16 + r15, k * 32 + hi * 8)];
        C[nt] = __builtin_amdgcn_mfma_f32_16x16x32_bf16(af, st[k], k == 0 ? Z4 : C[nt], 0, 0, 0);
      }
#pragma unroll
    for (int nt = 0; nt < 8; nt++) {
      f32x4 bv = *(const f32x4*)&bias[2][nt * 16 + hi * 4];
#pragma unroll
      for (int q = 0; q < 4; q++) xv[nt][q] = xr[nt][q] + silu_f(C[nt][q] + bv[q]);
    }
    exchCtoB(scw, r15, hi, xv, st);

    // ---- l3: x = silu(x@Wskip + b) + msg; store bf16
#pragma unroll
    for (int k = 0; k < 4; k++)
#pragma unroll
      for (int nt = 0; nt < 8; nt++) {
        s16x8 af = *(const s16x8*)&wb[3][swz(nt * 16 + r15, k * 32 + hi * 8)];
        C[nt] = __builtin_amdgcn_mfma_f32_16x16x32_bf16(af, st[k], k == 0 ? Z4 : C[nt], 0, 0, 0);
      }
    u32x2 mc[8];
    exchBtoC(scw, r15, hi, mg, mc);
#pragma unroll
    for (int nt = 0; nt < 8; nt++) {
      f32x4 bv = *(const f32x4*)&bias[3][nt * 16 + hi * 4];
      f32x4 m0;
      m0[0] = __uint_as_float(mc[nt][0] << 16);
      m0[1] = __uint_as_float(mc[nt][0] & 0xffff0000u);
      m0[2] = __uint_as_float(mc[nt][1] << 16);
      m0[3] = __uint_as_float(mc[nt][1] & 0xffff0000u);
      u32x2 pk;
      float o0 = silu_f(C[nt][0] + bv[0]) + m0[0];
      float o1 = silu_f(C[nt][1] + bv[1]) + m0[1];
      float o2 = silu_f(C[nt][2] + bv[2]) + m0[2];
      float o3 = silu_f(C[nt][3] + bv[3]) + m0[3];
      pk[0] = cvtpk(o0, o1);
      pk[1] = cvtpk(o2, o3);
      if (ok) *(u32x2*)&xmid[gb + nt * 16 + hi * 4] = pk;
    }
  }
}

// ---------------- K4b: post layers 4..7 (1 blk/CU; grid=256 balanced) --------
__global__ __launch_bounds__(512) void k_postB(const ushort* __restrict__ xmid,
                                               const ushort* __restrict__ wg_lin,
                                               const float* __restrict__ bias_tab,
                                               float* __restrict__ xout) {
  __shared__ ushort wb[4][16384];
  __shared__ ushort sc[8][1024];
  __shared__ float bias[4][128];
  int t = threadIdx.x;
  int lane = t & 63, w = t >> 6;
  int r15 = lane & 15, hi = lane >> 4;
  ushort* scw = &sc[w][0];
  const f32x4 Z4 = {0.f, 0.f, 0.f, 0.f};

#pragma unroll
  for (int s = 0; s < 4; s++) {
    const ushort* gs = wg_lin + (s + 5) * 16384 + t * 8;
    ushort* ls = &wb[s][t * 8];
#pragma unroll
    for (int i = 0; i < 4; i++)
      __builtin_amdgcn_global_load_lds(
          (const __attribute__((address_space(1))) void*)(gs + i * 4096),
          (__attribute__((address_space(3))) void*)(ls + i * 4096), 16, 0, 0);
  }
  if (t < 128) {
#pragma unroll
    for (int s = 0; s < 4; s++) bias[s][t] = bias_tab[(s + 5) * 128 + t];
  }
  __syncthreads();

#pragma unroll 1
  for (int tb = blockIdx.x; tb < 1563; tb += 256) {
    int r = tb * 128 + w * 16 + r15;
    bool ok = r < E_N;
    size_t gb = (size_t)r * 128;

    s16x8 st[4];
#pragma unroll
    for (int k = 0; k < 4; k++) {
      s16x8 z; u32x4 zz; zz[0] = 0; zz[1] = 0; zz[2] = 0; zz[3] = 0;
      z = __builtin_bit_cast(s16x8, zz);
      st[k] = ok ? *(const s16x8*)&xmid[gb + k * 32 + hi * 8] : z;
    }
    u32x2 mc[8];
    exchBtoC(scw, r15, hi, st, mc);
    f32x4 xr[8], xv[8], C[8];
#pragma unroll
    for (int nt = 0; nt < 8; nt++) {
      xr[nt][0] = __uint_as_float(mc[nt][0] << 16);
      xr[nt][1] = __uint_as_float(mc[nt][0] & 0xffff0000u);
      xr[nt][2] = __uint_as_float(mc[nt][1] << 16);
      xr[nt][3] = __uint_as_float(mc[nt][1] & 0xffff0000u);
    }

    // ---- l4
#pragma unroll
    for (int k = 0; k < 4; k++)
#pragma unroll
      for (int nt = 0; nt < 8; nt++) {
        s16x8 af = *(const s16x8*)&wb[0][swz(nt * 16 + r15, k * 32 + hi * 8)];
        C[nt] = __builtin_amdgcn_mfma_f32_16x16x32_bf16(af, st[k], k == 0 ? Z4 : C[nt], 0, 0, 0);
      }
#pragma unroll
    for (int nt = 0; nt < 8; nt++) {
      f32x4 bv = *(const f32x4*)&bias[0][nt * 16 + hi * 4];
#pragma unroll
      for (int q = 0; q < 4; q++) xv[nt][q] = silu_f(C[nt][q] + bv[q]);
    }
    exchCtoB(scw, r15, hi, xv, st);

    // ---- l5
#pragma unroll
    for (int k = 0; k < 4; k++)
#pragma unroll
      for (int nt = 0; nt < 8; nt++) {
        s16x8 af = *(const s16x8*)&wb[1][swz(nt * 16 + r15, k * 32 + hi * 8)];
        C[nt] = __builtin_amdgcn_mfma_f32_16x16x32_bf16(af, st[k], k == 0 ? Z4 : C[nt], 0, 0, 0);
      }
#pragma unroll
    for (int nt = 0; nt < 8; nt++) {
      f32x4 bv = *(const f32x4*)&bias[1][nt * 16 + hi * 4];
#pragma unroll
      for (int q = 0; q < 4; q++) xv[nt][q] = xr[nt][q] + silu_f(C[nt][q] + bv[q]);
      xr[nt] = xv[nt];
    }
    exchCtoB(scw, r15, hi, xv, st);

    // ---- l6
#pragma unroll
    for (int k = 0; k < 4; k++)
#pragma unroll
      for (int nt = 0; nt < 8; nt++) {
        s16x8 af = *(const s16x8*)&wb[2][swz(nt * 16 + r15, k * 32 + hi * 8)];
        C[nt] = __builtin_amdgcn_mfma_f32_16x16x32_bf16(af, st[k], k == 0 ? Z4 : C[nt], 0, 0, 0);
      }
#pragma unroll
    for (int nt = 0; nt < 8; nt++) {
      f32x4 bv = *(const f32x4*)&bias[2][nt * 16 + hi * 4];
#pragma unroll
      for (int q = 0; q < 4; q++) xv[nt][q] = silu_f(C[nt][q] + bv[q]);
    }
    exchCtoB(scw, r15, hi, xv, st);

    // ---- l7
#pragma unroll
    for (int k = 0; k < 4; k++)
#pragma unroll
      for (int nt = 0; nt < 8; nt++) {
        s16x8 af = *(const s16x8*)&wb[3][swz(nt * 16 + r15, k * 32 + hi * 8)];
        C[nt] = __builtin_amdgcn_mfma_f32_16x16x32_bf16(af, st[k], k == 0 ? Z4 : C[nt], 0, 0, 0);
      }
#pragma unroll
    for (int nt = 0; nt < 8; nt++) {
      f32x4 bv = *(const f32x4*)&bias[3][nt * 16 + hi * 4];
      f32x4 o;
#pragma unroll
      for (int q = 0; q < 4; q++) o[q] = xr[nt][q] + silu_f(C[nt][q] + bv[q]);
      if (ok) *(f32x4*)&xout[gb + nt * 16 + hi * 4] = o;
    }
  }
}

extern "C" void kernel_launch(void* const* d_in, const int* in_sizes, int n_in,
                              void* d_out, int out_size, void* d_ws, size_t ws_size,
                              hipStream_t stream) {
  const float* dist  = (const float*)d_in[0];
  const float* ang   = (const float*)d_in[1];
  const float* msg   = (const float*)d_in[2];
  const int*   aidx  = (const int*)d_in[3];
  const float* Wd    = (const float*)d_in[4];
  const float* Wang  = (const float*)d_in[5];
  const float* Wsrc  = (const float*)d_in[6];
  const float* bsrc  = (const float*)d_in[7];
  const float* Wtgt  = (const float*)d_in[8];
  const float* btgt  = (const float*)d_in[9];
  const float* Wbil  = (const float*)d_in[10];
  const float* WresB = (const float*)d_in[11];
  const float* bresB = (const float*)d_in[12];
  const float* Wskip = (const float*)d_in[13];
  const float* bskip = (const float*)d_in[14];
  const float* WresA = (const float*)d_in[15];
  const float* bresA = (const float*)d_in[16];

  char* ws = (char*)d_ws;
  ushort* srcm_f16 = (ushort*)(ws + 0);
  ushort* dtab_f16 = (ushort*)(ws + 51200000LL);
  float*  a_ws     = (float*)(ws + 102400000LL);
  ushort* wg_bil   = (ushort*)(ws + 134400000LL);
  ushort* wg_lin   = (ushort*)(ws + 134662144LL);
  float*  bias_tab = (float*)(ws + 134957056LL);
  int*    cnt      = (int*)(ws + 134961664LL);
  int*    cursor   = (int*)(ws + 135761664LL);
  int*    excl     = (int*)(ws + 136561664LL);
  int*    bsum     = (int*)(ws + 137361664LL);
  int*    ste      = (int*)(ws + 141362688LL);
  ushort* xmid     = (ushort*)(ws + 145362688LL);
  int*    sse      = (int*)(ws + 196562688LL);
  u32x4*  a_srt    = (u32x4*)(ws + 200562688LL);
  float*  agg      = (float*)d_out;

  (void)in_sizes; (void)n_in; (void)out_size; (void)ws_size;

  const int NSCAN = (E_N + 1023) / 1024;  // 196

  hipMemsetAsync(d_out, 0, (size_t)E_N * 128 * 4, stream);
  hipMemsetAsync(cnt, 0, (size_t)E_N * 4, stream);
  k_prep<<<1093, 256, 0, stream>>>(Wbil, Wsrc, Wtgt, WresB, Wskip, WresA,
                                   bsrc, btgt, bresB, bskip, bresA,
                                   wg_bil, wg_lin, bias_tab);
  k_angle<<<7813, 256, 0, stream>>>(ang, Wang, a_ws);
  k_hist<<<3907, 256, 0, stream>>>(aidx, cnt);
  k_scan1<<<NSCAN, 256, 0, stream>>>(cnt, excl, bsum);
  k_scan2<<<1, 256, 0, stream>>>(bsum, NSCAN);
  k_scan3<<<NSCAN, 256, 0, stream>>>(excl, bsum, cursor);
  k_scatter<<<3907, 256, 0, stream>>>(aidx, cursor, a_ws, ste, sse, a_srt);
  k_dist<<<3125, 256, 0, stream>>>(dist, Wd, dtab_f16);
  k_srcm<<<1563, 512, 0, stream>>>(msg, wg_lin, bias_tab, srcm_f16);
  k_bil<<<7813, 256, 0, stream>>>(sse, srcm_f16, dtab_f16, a_srt, wg_bil,
                                  ste, agg);
  k_postA<<<256, 512, 0, stream>>>(msg, agg, wg_lin, bias_tab, xmid);
  k_postB<<<256, 512, 0, stream>>>(xmid, wg_lin, bias_tab, (float*)d_out);
}